// Round 21
// baseline (166.791 us; speedup 1.0000x reference)
//
#include <hip/hip_runtime.h>

#define NPTS 4096
#define NBATCH 4
#define HDIM 192
#define CDIM 384

typedef _Float16 f16x8 __attribute__((ext_vector_type(8)));
typedef float f32x4 __attribute__((ext_vector_type(4)));

// ---------------- K0: W2 [192][384] f32 -> fragment-major f16 chunks (R12, unchanged) --
__global__ __launch_bounds__(256) void prep_w2(const float* __restrict__ W2,
                                               _Float16* __restrict__ W2F) {
  const int j = blockIdx.x * 256 + threadIdx.x;   // 9216 chunks
  if (j < 9216) {
    const int lane = j & 63, r = lane & 15, kg = lane >> 4;
    const int kt = (j >> 6) % 6, ct = j / 384;
    const int c = ct * 16 + r, h0 = kt * 32 + kg * 8;
    f16x8 v;
#pragma unroll
    for (int e = 0; e < 8; ++e) v[e] = (_Float16)W2[(size_t)(h0 + e) * CDIM + c];
    *(f16x8*)(W2F + (size_t)j * 8) = v;
  }
}

// ---------------- K1: KNN — R12 VERBATIM (91us; frozen after R13-R16 regressions) ------
#define SCAP 30
#define FINF 3.4e38f

// macro, not lambda: a [&] lambda address-takes dl/il -> scratch spill (R2 lesson)
#define PRUNE()                                                                      \
  do {                                                                               \
    int mc = cnt;                                                                    \
    _Pragma("unroll")                                                                \
    for (int s = 32; s; s >>= 1) { int o = __shfl_xor(mc, s); mc = mc > o ? mc : o; }\
    mc = __builtin_amdgcn_readfirstlane(mc);                                         \
    for (int e = 0; e < mc; ++e) {                                                   \
      const int j = sstk[sbase + e] & 4095;                                          \
      const float dx = qx - spx[j];                                                  \
      const float dy = qy - spy[j];                                                  \
      const float dz = qz - spz[j];                                                  \
      const float d = __fadd_rn(__fadd_rn(__fmul_rn(dx, dx), __fmul_rn(dy, dy)),     \
                                __fmul_rn(dz, dz));                                  \
      const float v = (e < cnt && d < dl[15]) ? d : FINF;                            \
      bool cc[16];                                                                   \
      _Pragma("unroll")                                                              \
      for (int i = 0; i < 16; ++i) cc[i] = v < dl[i];                                \
      _Pragma("unroll")                                                              \
      for (int i = 15; i >= 1; --i) {                                                \
        dl[i] = cc[i] ? (cc[i - 1] ? dl[i - 1] : v) : dl[i];                         \
        il[i] = cc[i] ? (cc[i - 1] ? il[i - 1] : j) : il[i];                         \
      }                                                                              \
      dl[0] = cc[0] ? v : dl[0];                                                     \
      il[0] = cc[0] ? j : il[0];                                                     \
    }                                                                                \
    cnt = 0;                                                                         \
    thr = dl[15];                                                                    \
    atomicMin(&sThrU[ql], __float_as_uint(dl[15]));                                  \
  } while (0)

__global__ __launch_bounds__(512) void knn_kernel(const float* __restrict__ pts,
                                                  int* __restrict__ idx_out) {
  __shared__ float smem[12352];
  __shared__ float sstk_f[7680];
  __shared__ unsigned sThrU[32];
  unsigned short* sstk = (unsigned short*)sstk_f;

  float* spx = smem;
  float* spy = smem + 4096;
  float* spz = smem + 8192;

  const int t  = threadIdx.x;
  const int b  = blockIdx.x >> 7;
  const int qb = (blockIdx.x & 127) << 5;
  const float* P = pts + (size_t)b * NPTS * 3;

  for (int i = t; i < NPTS; i += 512) {
    spx[i] = P[3 * i + 0];
    spy[i] = P[3 * i + 1];
    spz[i] = P[3 * i + 2];
  }
  if (t < 32) sThrU[t] = __float_as_uint(FINF);
  __syncthreads();

  const int ql    = t & 31;
  const int q     = qb + ql;
  const int cid   = (t >> 5) & 15;
  const int cbase = cid << 8;
  const float qx = spx[q], qy = spy[q], qz = spz[q];

  float dl[16];
  int   il[16];
#pragma unroll
  for (int i = 0; i < 16; ++i) { dl[i] = FINF; il[i] = 0; }
  float thr = FINF;
  int   cnt = 0;
  const int sbase = t * SCAP;

  for (int jt = 0; jt < 256; jt += 8) {
    {  // refresh admission threshold (volatile: must observe other waves' atomicMin)
      const unsigned tb = ((volatile unsigned*)sThrU)[ql];
      thr = fminf(dl[15], __uint_as_float(tb));
    }
    const int jb = cbase + jt;
    const f32x4 x0 = *(const f32x4*)(spx + jb);
    const f32x4 x1 = *(const f32x4*)(spx + jb + 4);
    const f32x4 y0 = *(const f32x4*)(spy + jb);
    const f32x4 y1 = *(const f32x4*)(spy + jb + 4);
    const f32x4 z0 = *(const f32x4*)(spz + jb);
    const f32x4 z1 = *(const f32x4*)(spz + jb + 4);
#pragma unroll
    for (int u = 0; u < 8; ++u) {
      const float px = (u < 4) ? x0[u & 3] : x1[u & 3];
      const float py = (u < 4) ? y0[u & 3] : y1[u & 3];
      const float pz = (u < 4) ? z0[u & 3] : z1[u & 3];
      const float dx = qx - px;
      const float dy = qy - py;
      const float dz = qz - pz;
      // EXACT match to numpy/jax: ((dx*dx + dy*dy) + dz*dz), f32, no FMA contraction
      const float d = __fadd_rn(__fadd_rn(__fmul_rn(dx, dx), __fmul_rn(dy, dy)),
                                __fmul_rn(dz, dz));
      if (d <= thr) { sstk[sbase + cnt] = (unsigned short)(jb + u); ++cnt; }
    }
    if (__any(cnt >= SCAP - 8)) PRUNE();
  }
  PRUNE();

  __syncthreads();

  float*          md = smem;
  unsigned short* mi = (unsigned short*)(smem + 8224);
  const int lbase = ql * 257 + cid * 16;
#pragma unroll
  for (int i = 0; i < 16; ++i) {
    md[lbase + i] = dl[i];
    mi[lbase + i] = (unsigned short)il[i];
  }
  __syncthreads();

  float*          od = sstk_f;
  unsigned short* oi = (unsigned short*)(sstk_f + 2080);
  if (t < 128) {
    const int mq = t >> 2, g = t & 3;
    const int base = mq * 257 + g * 64;
    int p0 = 0, p1 = 0, p2 = 0, p3 = 0;
    const int ob = mq * 65 + g * 16;
    for (int r = 0; r < 16; ++r) {
      const float d0 = md[base + p0];
      const float d1 = md[base + 16 + p1];
      const float d2 = md[base + 32 + p2];
      const float d3 = md[base + 48 + p3];
      int bw = 0; float bd = d0;
      if (d1 < bd) { bd = d1; bw = 1; }
      if (d2 < bd) { bd = d2; bw = 2; }
      if (d3 < bd) { bd = d3; bw = 3; }
      const unsigned short bi = (bw == 0) ? mi[base + p0]
                              : (bw == 1) ? mi[base + 16 + p1]
                              : (bw == 2) ? mi[base + 32 + p2]
                                          : mi[base + 48 + p3];
      od[ob + r] = bd;
      oi[ob + r] = bi;
      p0 += (bw == 0); p1 += (bw == 1); p2 += (bw == 2); p3 += (bw == 3);
    }
  }
  __syncthreads();

  if (t < 32) {
    const int base = t * 65;
    int p0 = 0, p1 = 0, p2 = 0, p3 = 0;
    int* op = idx_out + (((size_t)b * NPTS + qb + t) << 4);
    for (int r = 0; r < 16; ++r) {
      const float d0 = od[base + p0];
      const float d1 = od[base + 16 + p1];
      const float d2 = od[base + 32 + p2];
      const float d3 = od[base + 48 + p3];
      int bw = 0; float bd = d0;
      if (d1 < bd) { bd = d1; bw = 1; }
      if (d2 < bd) { bd = d2; bw = 2; }
      if (d3 < bd) { bd = d3; bw = 3; }
      const unsigned short bi = (bw == 0) ? oi[base + p0]
                              : (bw == 1) ? oi[base + 16 + p1]
                              : (bw == 2) ? oi[base + 32 + p2]
                                          : oi[base + 48 + p3];
      op[r] = (int)bi;
      p0 += (bw == 0); p1 += (bw == 1); p2 += (bw == 2); p3 += (bw == 3);
    }
  }
}

// ---------------- K2: fused MLP — half-W2 in LDS (72KB), 2q/wave, EXPLICIT (512,4) ----
// Joint constraint (R9/R17/R18/R19/R20): residency x regs <= 2048/SIMD AND LDS x blocks
// <= 160KB. The only 4-waves/SIMD point: <=128 regs (=> 2q/wave, ~110 demand) and
// <=80KB LDS (=> half of W2). (512,4) pins the 128 budget. 2 blocks/CU: one block's
// 72KB fill overlaps the other's MFMA. 2048 blocks = 16 queries x half-channels each.
// Staging math + fragment layout byte-identical to R12 (numerics unchanged).
__global__ __launch_bounds__(512, 4) void mlp_kernel(const float* __restrict__ pts,
                                                     const int* __restrict__ idx,
                                                     const float* __restrict__ W1,
                                                     const float* __restrict__ b1,
                                                     const _Float16* __restrict__ W2F,
                                                     const float* __restrict__ b2,
                                                     float* __restrict__ out) {
  __shared__ _Float16 sB[36864];       // 72 KiB: half of W2, fragment-major

  const int bid = blockIdx.x;          // 2048 = 4 batches * 256 groups(16q) * 2 halves
  const int b   = bid >> 9;
  const int g   = bid & 511;
  const int qg  = g >> 1;              // query group 0..255 (16 queries)
  const int h   = g & 1;               // W2 half: ct-tiles 12h .. 12h+11
  const int t   = threadIdx.x;
  const int wv  = t >> 6;              // 8 waves
  const int q0  = (qg << 4) + (wv << 1);   // queries q0, q0+1
  const float* P = pts + (size_t)b * NPTS * 3;
  const int l   = t & 63;
  const int r   = l & 15;
  const int kg  = l >> 4;

  // ---- fill LDS with this half's 4608 chunks (lane-linear, conflict-free) ----
#pragma unroll
  for (int i = 0; i < 9; ++i) {
    const int jl = i * 512 + t;
    *(f16x8*)(sB + (size_t)jl * 8) = *(const f16x8*)(W2F + (size_t)(h * 4608 + jl) * 8);
  }

  // ---- gathers: 2 queries, neighbor slot r each ----
  float f[2][6];
#pragma unroll
  for (int qi = 0; qi < 2; ++qi) {
    const int qq = q0 + qi;
    const int nb = idx[(((size_t)b * NPTS + qq) << 4) + r];
    const float ax = P[qq * 3 + 0], ay = P[qq * 3 + 1], az = P[qq * 3 + 2];
    f[qi][0] = P[nb * 3 + 0] - ax;
    f[qi][1] = P[nb * 3 + 1] - ay;
    f[qi][2] = P[nb * 3 + 2] - az;
    f[qi][3] = ax; f[qi][4] = ay; f[qi][5] = az;
  }

  // ---- stage layer1 -> A-fragments in registers (identical numerics to R12) ----
  f16x8 af[2][6];
#pragma unroll
  for (int kt = 0; kt < 6; ++kt) {
    const int h0 = kt * 32 + kg * 8;
#pragma unroll
    for (int qi = 0; qi < 2; ++qi) {
      f32x4 a0 = *(const f32x4*)(b1 + h0);
      f32x4 a1 = *(const f32x4*)(b1 + h0 + 4);
#pragma unroll
      for (int in = 0; in < 6; ++in) {
        a0 += f[qi][in] * *(const f32x4*)(W1 + in * HDIM + h0);
        a1 += f[qi][in] * *(const f32x4*)(W1 + in * HDIM + h0 + 4);
      }
      f16x8 v;
#pragma unroll
      for (int j = 0; j < 4; ++j) {   // same swish expression as R4..R20 (absmax-stable)
        v[j]     = (_Float16)(a0[j] * __builtin_amdgcn_rcpf(1.0f + __expf(-a0[j])));
        v[j + 4] = (_Float16)(a1[j] * __builtin_amdgcn_rcpf(1.0f + __expf(-a1[j])));
      }
      af[qi][kt] = v;
    }
  }
  __syncthreads();   // LDS fill complete (fill loads + staging overlap above)

  // ---- MFMA + maxpool over this half's 12 channel tiles; B from LDS ----
  const size_t orow = (size_t)b * NPTS + q0;
  const _Float16* bp = sB + (size_t)l * 8;   // chunk position == lane

  for (int ct = 0; ct < 12; ++ct) {
    const int c = (h * 12 + ct) * 16 + r;    // global output channel
    f16x8 bfr[6];
#pragma unroll
    for (int kt = 0; kt < 6; ++kt)
      bfr[kt] = *(const f16x8*)(bp + (size_t)(ct * 6 + kt) * 512);  // local chunk offset

    f32x4 acc0 = {0.f, 0.f, 0.f, 0.f};
    f32x4 acc1 = {0.f, 0.f, 0.f, 0.f};
#pragma unroll
    for (int kt = 0; kt < 6; ++kt) {
      acc0 = __builtin_amdgcn_mfma_f32_16x16x32_f16(af[0][kt], bfr[kt], acc0, 0, 0, 0);
      acc1 = __builtin_amdgcn_mfma_f32_16x16x32_f16(af[1][kt], bfr[kt], acc1, 0, 0, 0);
    }

    const float bb = b2[c];
    // C/D: col=lane&15 (=channel), row=(lane>>4)*4+reg (=neighbor) -> max over rows
    float m0 = fmaxf(fmaxf(acc0[0], acc0[1]), fmaxf(acc0[2], acc0[3]));
    m0 = fmaxf(m0, __shfl_xor(m0, 16));
    m0 = fmaxf(m0, __shfl_xor(m0, 32));
    float m1 = fmaxf(fmaxf(acc1[0], acc1[1]), fmaxf(acc1[2], acc1[3]));
    m1 = fmaxf(m1, __shfl_xor(m1, 16));
    m1 = fmaxf(m1, __shfl_xor(m1, 32));
    if (l < 16) {
      out[(orow + 0) * CDIM + c] = m0 + bb;
      out[(orow + 1) * CDIM + c] = m1 + bb;
    }
  }
}

extern "C" void kernel_launch(void* const* d_in, const int* in_sizes, int n_in,
                              void* d_out, int out_size, void* d_ws, size_t ws_size,
                              hipStream_t stream) {
  const float* point = (const float*)d_in[0];
  const float* W1    = (const float*)d_in[1];
  const float* b1    = (const float*)d_in[2];
  const float* W2    = (const float*)d_in[3];
  const float* b2    = (const float*)d_in[4];

  int*      idx_ws = (int*)d_ws;                                  // 1 MB
  _Float16* W2F    = (_Float16*)((char*)d_ws + (1 << 20));        // 144 KB

  prep_w2<<<36, 256, 0, stream>>>(W2, W2F);
  knn_kernel<<<512, 512, 0, stream>>>(point, idx_ws);
  mlp_kernel<<<2048, 512, 0, stream>>>(point, idx_ws, W1, b1, W2F, b2, (float*)d_out);
}

// Round 22
// 150.557 us; speedup vs baseline: 1.1078x; 1.1078x over previous
//
#include <hip/hip_runtime.h>

#define NPTS 4096
#define NBATCH 4
#define HDIM 192
#define CDIM 384

typedef _Float16 f16x8 __attribute__((ext_vector_type(8)));
typedef float f32x4 __attribute__((ext_vector_type(4)));

// ---------------- K0: W2 [192][384] f32 -> fragment-major f16 chunks (R12, unchanged) --
__global__ __launch_bounds__(256) void prep_w2(const float* __restrict__ W2,
                                               _Float16* __restrict__ W2F) {
  const int j = blockIdx.x * 256 + threadIdx.x;   // 9216 chunks
  if (j < 9216) {
    const int lane = j & 63, r = lane & 15, kg = lane >> 4;
    const int kt = (j >> 6) % 6, ct = j / 384;
    const int c = ct * 16 + r, h0 = kt * 32 + kg * 8;
    f16x8 v;
#pragma unroll
    for (int e = 0; e < 8; ++e) v[e] = (_Float16)W2[(size_t)(h0 + e) * CDIM + c];
    *(f16x8*)(W2F + (size_t)j * 8) = v;
  }
}

// ---------------- K1: KNN — R12 VERBATIM (91us; frozen after R13-R16 regressions) ------
#define SCAP 30
#define FINF 3.4e38f

// macro, not lambda: a [&] lambda address-takes dl/il -> scratch spill (R2 lesson)
#define PRUNE()                                                                      \
  do {                                                                               \
    int mc = cnt;                                                                    \
    _Pragma("unroll")                                                                \
    for (int s = 32; s; s >>= 1) { int o = __shfl_xor(mc, s); mc = mc > o ? mc : o; }\
    mc = __builtin_amdgcn_readfirstlane(mc);                                         \
    for (int e = 0; e < mc; ++e) {                                                   \
      const int j = sstk[sbase + e] & 4095;                                          \
      const float dx = qx - spx[j];                                                  \
      const float dy = qy - spy[j];                                                  \
      const float dz = qz - spz[j];                                                  \
      const float d = __fadd_rn(__fadd_rn(__fmul_rn(dx, dx), __fmul_rn(dy, dy)),     \
                                __fmul_rn(dz, dz));                                  \
      const float v = (e < cnt && d < dl[15]) ? d : FINF;                            \
      bool cc[16];                                                                   \
      _Pragma("unroll")                                                              \
      for (int i = 0; i < 16; ++i) cc[i] = v < dl[i];                                \
      _Pragma("unroll")                                                              \
      for (int i = 15; i >= 1; --i) {                                                \
        dl[i] = cc[i] ? (cc[i - 1] ? dl[i - 1] : v) : dl[i];                         \
        il[i] = cc[i] ? (cc[i - 1] ? il[i - 1] : j) : il[i];                         \
      }                                                                              \
      dl[0] = cc[0] ? v : dl[0];                                                     \
      il[0] = cc[0] ? j : il[0];                                                     \
    }                                                                                \
    cnt = 0;                                                                         \
    thr = dl[15];                                                                    \
    atomicMin(&sThrU[ql], __float_as_uint(dl[15]));                                  \
  } while (0)

__global__ __launch_bounds__(512) void knn_kernel(const float* __restrict__ pts,
                                                  int* __restrict__ idx_out) {
  __shared__ float smem[12352];
  __shared__ float sstk_f[7680];
  __shared__ unsigned sThrU[32];
  unsigned short* sstk = (unsigned short*)sstk_f;

  float* spx = smem;
  float* spy = smem + 4096;
  float* spz = smem + 8192;

  const int t  = threadIdx.x;
  const int b  = blockIdx.x >> 7;
  const int qb = (blockIdx.x & 127) << 5;
  const float* P = pts + (size_t)b * NPTS * 3;

  for (int i = t; i < NPTS; i += 512) {
    spx[i] = P[3 * i + 0];
    spy[i] = P[3 * i + 1];
    spz[i] = P[3 * i + 2];
  }
  if (t < 32) sThrU[t] = __float_as_uint(FINF);
  __syncthreads();

  const int ql    = t & 31;
  const int q     = qb + ql;
  const int cid   = (t >> 5) & 15;
  const int cbase = cid << 8;
  const float qx = spx[q], qy = spy[q], qz = spz[q];

  float dl[16];
  int   il[16];
#pragma unroll
  for (int i = 0; i < 16; ++i) { dl[i] = FINF; il[i] = 0; }
  float thr = FINF;
  int   cnt = 0;
  const int sbase = t * SCAP;

  for (int jt = 0; jt < 256; jt += 8) {
    {  // refresh admission threshold (volatile: must observe other waves' atomicMin)
      const unsigned tb = ((volatile unsigned*)sThrU)[ql];
      thr = fminf(dl[15], __uint_as_float(tb));
    }
    const int jb = cbase + jt;
    const f32x4 x0 = *(const f32x4*)(spx + jb);
    const f32x4 x1 = *(const f32x4*)(spx + jb + 4);
    const f32x4 y0 = *(const f32x4*)(spy + jb);
    const f32x4 y1 = *(const f32x4*)(spy + jb + 4);
    const f32x4 z0 = *(const f32x4*)(spz + jb);
    const f32x4 z1 = *(const f32x4*)(spz + jb + 4);
#pragma unroll
    for (int u = 0; u < 8; ++u) {
      const float px = (u < 4) ? x0[u & 3] : x1[u & 3];
      const float py = (u < 4) ? y0[u & 3] : y1[u & 3];
      const float pz = (u < 4) ? z0[u & 3] : z1[u & 3];
      const float dx = qx - px;
      const float dy = qy - py;
      const float dz = qz - pz;
      // EXACT match to numpy/jax: ((dx*dx + dy*dy) + dz*dz), f32, no FMA contraction
      const float d = __fadd_rn(__fadd_rn(__fmul_rn(dx, dx), __fmul_rn(dy, dy)),
                                __fmul_rn(dz, dz));
      if (d <= thr) { sstk[sbase + cnt] = (unsigned short)(jb + u); ++cnt; }
    }
    if (__any(cnt >= SCAP - 8)) PRUNE();
  }
  PRUNE();

  __syncthreads();

  float*          md = smem;
  unsigned short* mi = (unsigned short*)(smem + 8224);
  const int lbase = ql * 257 + cid * 16;
#pragma unroll
  for (int i = 0; i < 16; ++i) {
    md[lbase + i] = dl[i];
    mi[lbase + i] = (unsigned short)il[i];
  }
  __syncthreads();

  float*          od = sstk_f;
  unsigned short* oi = (unsigned short*)(sstk_f + 2080);
  if (t < 128) {
    const int mq = t >> 2, g = t & 3;
    const int base = mq * 257 + g * 64;
    int p0 = 0, p1 = 0, p2 = 0, p3 = 0;
    const int ob = mq * 65 + g * 16;
    for (int r = 0; r < 16; ++r) {
      const float d0 = md[base + p0];
      const float d1 = md[base + 16 + p1];
      const float d2 = md[base + 32 + p2];
      const float d3 = md[base + 48 + p3];
      int bw = 0; float bd = d0;
      if (d1 < bd) { bd = d1; bw = 1; }
      if (d2 < bd) { bd = d2; bw = 2; }
      if (d3 < bd) { bd = d3; bw = 3; }
      const unsigned short bi = (bw == 0) ? mi[base + p0]
                              : (bw == 1) ? mi[base + 16 + p1]
                              : (bw == 2) ? mi[base + 32 + p2]
                                          : mi[base + 48 + p3];
      od[ob + r] = bd;
      oi[ob + r] = bi;
      p0 += (bw == 0); p1 += (bw == 1); p2 += (bw == 2); p3 += (bw == 3);
    }
  }
  __syncthreads();

  if (t < 32) {
    const int base = t * 65;
    int p0 = 0, p1 = 0, p2 = 0, p3 = 0;
    int* op = idx_out + (((size_t)b * NPTS + qb + t) << 4);
    for (int r = 0; r < 16; ++r) {
      const float d0 = od[base + p0];
      const float d1 = od[base + 16 + p1];
      const float d2 = od[base + 32 + p2];
      const float d3 = od[base + 48 + p3];
      int bw = 0; float bd = d0;
      if (d1 < bd) { bd = d1; bw = 1; }
      if (d2 < bd) { bd = d2; bw = 2; }
      if (d3 < bd) { bd = d3; bw = 3; }
      const unsigned short bi = (bw == 0) ? oi[base + p0]
                              : (bw == 1) ? oi[base + 16 + p1]
                              : (bw == 2) ? oi[base + 32 + p2]
                                          : oi[base + 48 + p3];
      op[r] = (int)bi;
      p0 += (bw == 0); p1 += (bw == 1); p2 += (bw == 2); p3 += (bw == 3);
    }
  }
}

// ---------------- K2: fused MLP — R20 config, fill-once / compute-TWICE ---------------
// R21 settled the tradeoff: fill amortization > occupancy for this mlp (half-W2 at 4
// waves/SIMD lost ~20us to 2x fill traffic). So push R20's axis further: grid 256
// (1 block/CU), each block = R20's exact reg/LDS config ((512,2), full 144KB W2,
// 4q/wave, B-prefetch) but serves 64 queries in 2 UNROLLED rounds: fill W2 once,
// stage rnd-0 while fill in flight, ONE barrier, compute; stage rnd-1 (no barrier,
// sB read-only), compute. Halves fills+barriers vs R20. Numerics byte-identical.
__global__ __launch_bounds__(512, 2) void mlp_kernel(const float* __restrict__ pts,
                                                     const int* __restrict__ idx,
                                                     const float* __restrict__ W1,
                                                     const float* __restrict__ b1,
                                                     const _Float16* __restrict__ W2F,
                                                     const float* __restrict__ b2,
                                                     float* __restrict__ out) {
  __shared__ _Float16 sB[73728];       // 144 KiB: all of W2, fragment-major

  const int bid = blockIdx.x;          // 256 = 4 batches * 64 blocks (1 per CU)
  const int b   = bid >> 6;
  const int t   = threadIdx.x;
  const int wv  = t >> 6;              // 8 waves
  const float* P = pts + (size_t)b * NPTS * 3;
  const int l   = t & 63;
  const int r   = l & 15;
  const int kg  = l >> 4;

  // ---- fill LDS with all 9216 W2 chunks (lane-linear, conflict-free), ONCE ----
#pragma unroll
  for (int i = 0; i < 18; ++i) {
    const int j = i * 512 + t;
    *(f16x8*)(sB + (size_t)j * 8) = *(const f16x8*)(W2F + (size_t)j * 8);
  }

  const _Float16* bp = sB + (size_t)l * 8;   // chunk position == lane

#pragma unroll
  for (int rnd = 0; rnd < 2; ++rnd) {        // unrolled: rnd compile-time (SROA-safe)
    const int q0 = ((bid & 63) << 6) + (rnd << 5) + (wv << 2);   // 4 queries

    // ---- gathers: 4 queries, neighbor slot r each ----
    float f[4][6];
#pragma unroll
    for (int qi = 0; qi < 4; ++qi) {
      const int qq = q0 + qi;
      const int nb = idx[(((size_t)b * NPTS + qq) << 4) + r];
      const float ax = P[qq * 3 + 0], ay = P[qq * 3 + 1], az = P[qq * 3 + 2];
      f[qi][0] = P[nb * 3 + 0] - ax;
      f[qi][1] = P[nb * 3 + 1] - ay;
      f[qi][2] = P[nb * 3 + 2] - az;
      f[qi][3] = ax; f[qi][4] = ay; f[qi][5] = az;
    }

    // ---- stage layer1 -> A-fragments in registers (identical numerics to R12/R20) ----
    f16x8 af[4][6];
#pragma unroll
    for (int kt = 0; kt < 6; ++kt) {
      const int h0 = kt * 32 + kg * 8;
      const f32x4 bb0 = *(const f32x4*)(b1 + h0);
      const f32x4 bb1 = *(const f32x4*)(b1 + h0 + 4);
      f32x4 w0[6], w1[6];
#pragma unroll
      for (int in = 0; in < 6; ++in) {
        w0[in] = *(const f32x4*)(W1 + in * HDIM + h0);
        w1[in] = *(const f32x4*)(W1 + in * HDIM + h0 + 4);
      }
#pragma unroll
      for (int qi = 0; qi < 4; ++qi) {
        f32x4 a0 = bb0, a1 = bb1;
#pragma unroll
        for (int in = 0; in < 6; ++in) {
          a0 += f[qi][in] * w0[in];
          a1 += f[qi][in] * w1[in];
        }
        f16x8 v;
#pragma unroll
        for (int j = 0; j < 4; ++j) {   // same swish expression (absmax-stable)
          v[j]     = (_Float16)(a0[j] * __builtin_amdgcn_rcpf(1.0f + __expf(-a0[j])));
          v[j + 4] = (_Float16)(a1[j] * __builtin_amdgcn_rcpf(1.0f + __expf(-a1[j])));
        }
        af[qi][kt] = v;
      }
    }

    if (rnd == 0) __syncthreads();   // fill visible before first sB reads

    // ---- MFMA + maxpool over 24 channel tiles; B from LDS, software-pipelined ----
    const size_t orow = (size_t)b * NPTS + q0;

    f16x8 bcur[6];
#pragma unroll
    for (int kt = 0; kt < 6; ++kt)
      bcur[kt] = *(const f16x8*)(bp + (size_t)kt * 512);   // ct=0

    for (int ct = 0; ct < 24; ++ct) {
      const int c = ct * 16 + r;
      // prefetch next ct's B-frags (hides LDS latency under MFMAs)
      f16x8 bnxt[6];
      const int ctn = (ct < 23) ? ct + 1 : 23;
#pragma unroll
      for (int kt = 0; kt < 6; ++kt)
        bnxt[kt] = *(const f16x8*)(bp + (size_t)(ctn * 6 + kt) * 512);

      f32x4 acc[4];
#pragma unroll
      for (int qi = 0; qi < 4; ++qi) acc[qi] = f32x4{0.f, 0.f, 0.f, 0.f};
#pragma unroll
      for (int kt = 0; kt < 6; ++kt)
#pragma unroll
        for (int qi = 0; qi < 4; ++qi)
          acc[qi] = __builtin_amdgcn_mfma_f32_16x16x32_f16(af[qi][kt], bcur[kt], acc[qi], 0, 0, 0);

      const float bb = b2[c];
      // C/D: col=lane&15 (=channel), row=(lane>>4)*4+reg (=neighbor) -> max over rows
#pragma unroll
      for (int qi = 0; qi < 4; ++qi) {
        float m = fmaxf(fmaxf(acc[qi][0], acc[qi][1]), fmaxf(acc[qi][2], acc[qi][3]));
        m = fmaxf(m, __shfl_xor(m, 16));
        m = fmaxf(m, __shfl_xor(m, 32));
        if (l < 16)
          out[(orow + qi) * CDIM + c] = m + bb;
      }

#pragma unroll
      for (int kt = 0; kt < 6; ++kt) bcur[kt] = bnxt[kt];
    }
  }
}

extern "C" void kernel_launch(void* const* d_in, const int* in_sizes, int n_in,
                              void* d_out, int out_size, void* d_ws, size_t ws_size,
                              hipStream_t stream) {
  const float* point = (const float*)d_in[0];
  const float* W1    = (const float*)d_in[1];
  const float* b1    = (const float*)d_in[2];
  const float* W2    = (const float*)d_in[3];
  const float* b2    = (const float*)d_in[4];

  int*      idx_ws = (int*)d_ws;                                  // 1 MB
  _Float16* W2F    = (_Float16*)((char*)d_ws + (1 << 20));        // 144 KB

  prep_w2<<<36, 256, 0, stream>>>(W2, W2F);
  knn_kernel<<<512, 512, 0, stream>>>(point, idx_ws);
  mlp_kernel<<<256, 512, 0, stream>>>(point, idx_ws, W1, b1, W2F, b2, (float*)d_out);
}

// Round 23
// 146.736 us; speedup vs baseline: 1.1367x; 1.0260x over previous
//
#include <hip/hip_runtime.h>

#define NPTS 4096
#define NBATCH 4
#define HDIM 192
#define CDIM 384

typedef _Float16 f16x8 __attribute__((ext_vector_type(8)));
typedef float f32x4 __attribute__((ext_vector_type(4)));

// ---------------- K0: W2 [192][384] f32 -> fragment-major f16 chunks ----------------
__global__ __launch_bounds__(256) void prep_w2(const float* __restrict__ W2,
                                               _Float16* __restrict__ W2F) {
  const int j = blockIdx.x * 256 + threadIdx.x;   // 9216 chunks
  if (j < 9216) {
    const int lane = j & 63, r = lane & 15, kg = lane >> 4;
    const int kt = (j >> 6) % 6, ct = j / 384;
    const int c = ct * 16 + r, h0 = kt * 32 + kg * 8;
    f16x8 v;
#pragma unroll
    for (int e = 0; e < 8; ++e) v[e] = (_Float16)W2[(size_t)(h0 + e) * CDIM + c];
    *(f16x8*)(W2F + (size_t)j * 8) = v;
  }
}

// ---------------- K1: KNN — R12 VERBATIM (91us; frozen) ------
#define SCAP 30
#define FINF 3.4e38f

// macro, not lambda: a [&] lambda address-takes dl/il -> scratch spill (R2 lesson)
#define PRUNE()                                                                      \
  do {                                                                               \
    int mc = cnt;                                                                    \
    _Pragma("unroll")                                                                \
    for (int s = 32; s; s >>= 1) { int o = __shfl_xor(mc, s); mc = mc > o ? mc : o; }\
    mc = __builtin_amdgcn_readfirstlane(mc);                                         \
    for (int e = 0; e < mc; ++e) {                                                   \
      const int j = sstk[sbase + e] & 4095;                                          \
      const float dx = qx - spx[j];                                                  \
      const float dy = qy - spy[j];                                                  \
      const float dz = qz - spz[j];                                                  \
      const float d = __fadd_rn(__fadd_rn(__fmul_rn(dx, dx), __fmul_rn(dy, dy)),     \
                                __fmul_rn(dz, dz));                                  \
      const float v = (e < cnt && d < dl[15]) ? d : FINF;                            \
      bool cc[16];                                                                   \
      _Pragma("unroll")                                                              \
      for (int i = 0; i < 16; ++i) cc[i] = v < dl[i];                                \
      _Pragma("unroll")                                                              \
      for (int i = 15; i >= 1; --i) {                                                \
        dl[i] = cc[i] ? (cc[i - 1] ? dl[i - 1] : v) : dl[i];                         \
        il[i] = cc[i] ? (cc[i - 1] ? il[i - 1] : j) : il[i];                         \
      }                                                                              \
      dl[0] = cc[0] ? v : dl[0];                                                     \
      il[0] = cc[0] ? j : il[0];                                                     \
    }                                                                                \
    cnt = 0;                                                                         \
    thr = dl[15];                                                                    \
    atomicMin(&sThrU[ql], __float_as_uint(dl[15]));                                  \
  } while (0)

__global__ __launch_bounds__(512) void knn_kernel(const float* __restrict__ pts,
                                                  int* __restrict__ idx_out) {
  __shared__ float smem[12352];
  __shared__ float sstk_f[7680];
  __shared__ unsigned sThrU[32];
  unsigned short* sstk = (unsigned short*)sstk_f;

  float* spx = smem;
  float* spy = smem + 4096;
  float* spz = smem + 8192;

  const int t  = threadIdx.x;
  const int b  = blockIdx.x >> 7;
  const int qb = (blockIdx.x & 127) << 5;
  const float* P = pts + (size_t)b * NPTS * 3;

  for (int i = t; i < NPTS; i += 512) {
    spx[i] = P[3 * i + 0];
    spy[i] = P[3 * i + 1];
    spz[i] = P[3 * i + 2];
  }
  if (t < 32) sThrU[t] = __float_as_uint(FINF);
  __syncthreads();

  const int ql    = t & 31;
  const int q     = qb + ql;
  const int cid   = (t >> 5) & 15;
  const int cbase = cid << 8;
  const float qx = spx[q], qy = spy[q], qz = spz[q];

  float dl[16];
  int   il[16];
#pragma unroll
  for (int i = 0; i < 16; ++i) { dl[i] = FINF; il[i] = 0; }
  float thr = FINF;
  int   cnt = 0;
  const int sbase = t * SCAP;

  for (int jt = 0; jt < 256; jt += 8) {
    {  // refresh admission threshold (volatile: must observe other waves' atomicMin)
      const unsigned tb = ((volatile unsigned*)sThrU)[ql];
      thr = fminf(dl[15], __uint_as_float(tb));
    }
    const int jb = cbase + jt;
    const f32x4 x0 = *(const f32x4*)(spx + jb);
    const f32x4 x1 = *(const f32x4*)(spx + jb + 4);
    const f32x4 y0 = *(const f32x4*)(spy + jb);
    const f32x4 y1 = *(const f32x4*)(spy + jb + 4);
    const f32x4 z0 = *(const f32x4*)(spz + jb);
    const f32x4 z1 = *(const f32x4*)(spz + jb + 4);
#pragma unroll
    for (int u = 0; u < 8; ++u) {
      const float px = (u < 4) ? x0[u & 3] : x1[u & 3];
      const float py = (u < 4) ? y0[u & 3] : y1[u & 3];
      const float pz = (u < 4) ? z0[u & 3] : z1[u & 3];
      const float dx = qx - px;
      const float dy = qy - py;
      const float dz = qz - pz;
      // EXACT match to numpy/jax: ((dx*dx + dy*dy) + dz*dz), f32, no FMA contraction
      const float d = __fadd_rn(__fadd_rn(__fmul_rn(dx, dx), __fmul_rn(dy, dy)),
                                __fmul_rn(dz, dz));
      if (d <= thr) { sstk[sbase + cnt] = (unsigned short)(jb + u); ++cnt; }
    }
    if (__any(cnt >= SCAP - 8)) PRUNE();
  }
  PRUNE();

  __syncthreads();

  float*          md = smem;
  unsigned short* mi = (unsigned short*)(smem + 8224);
  const int lbase = ql * 257 + cid * 16;
#pragma unroll
  for (int i = 0; i < 16; ++i) {
    md[lbase + i] = dl[i];
    mi[lbase + i] = (unsigned short)il[i];
  }
  __syncthreads();

  float*          od = sstk_f;
  unsigned short* oi = (unsigned short*)(sstk_f + 2080);
  if (t < 128) {
    const int mq = t >> 2, g = t & 3;
    const int base = mq * 257 + g * 64;
    int p0 = 0, p1 = 0, p2 = 0, p3 = 0;
    const int ob = mq * 65 + g * 16;
    for (int r = 0; r < 16; ++r) {
      const float d0 = md[base + p0];
      const float d1 = md[base + 16 + p1];
      const float d2 = md[base + 32 + p2];
      const float d3 = md[base + 48 + p3];
      int bw = 0; float bd = d0;
      if (d1 < bd) { bd = d1; bw = 1; }
      if (d2 < bd) { bd = d2; bw = 2; }
      if (d3 < bd) { bd = d3; bw = 3; }
      const unsigned short bi = (bw == 0) ? mi[base + p0]
                              : (bw == 1) ? mi[base + 16 + p1]
                              : (bw == 2) ? mi[base + 32 + p2]
                                          : mi[base + 48 + p3];
      od[ob + r] = bd;
      oi[ob + r] = bi;
      p0 += (bw == 0); p1 += (bw == 1); p2 += (bw == 2); p3 += (bw == 3);
    }
  }
  __syncthreads();

  if (t < 32) {
    const int base = t * 65;
    int p0 = 0, p1 = 0, p2 = 0, p3 = 0;
    int* op = idx_out + (((size_t)b * NPTS + qb + t) << 4);
    for (int r = 0; r < 16; ++r) {
      const float d0 = od[base + p0];
      const float d1 = od[base + 16 + p1];
      const float d2 = od[base + 32 + p2];
      const float d3 = od[base + 48 + p3];
      int bw = 0; float bd = d0;
      if (d1 < bd) { bd = d1; bw = 1; }
      if (d2 < bd) { bd = d2; bw = 2; }
      if (d3 < bd) { bd = d3; bw = 3; }
      const unsigned short bi = (bw == 0) ? oi[base + p0]
                              : (bw == 1) ? oi[base + 16 + p1]
                              : (bw == 2) ? oi[base + 32 + p2]
                                          : oi[base + 48 + p3];
      op[r] = (int)bi;
      p0 += (bw == 0); p1 += (bw == 1); p2 += (bw == 2); p3 += (bw == 3);
    }
  }
}

// ---------------- K2: fused MLP — R20 VERBATIM (best: ~48us) ---------------
// (512,2): 256-reg budget, no spill; LDS (144KB) caps at 1 block/CU = 2 waves/EU
// regardless, so the bound costs zero occupancy. Full W2 in LDS, 4q/wave, B-prefetch
// pipeline. All variants tried (half-W2 x2, persistent x3) regressed or tied.
__global__ __launch_bounds__(512, 2) void mlp_kernel(const float* __restrict__ pts,
                                                     const int* __restrict__ idx,
                                                     const float* __restrict__ W1,
                                                     const float* __restrict__ b1,
                                                     const _Float16* __restrict__ W2F,
                                                     const float* __restrict__ b2,
                                                     float* __restrict__ out) {
  __shared__ _Float16 sB[73728];       // 144 KiB: all of W2, fragment-major

  const int bid = blockIdx.x;          // 512 = 4 batches * 128 blocks
  const int b   = bid >> 7;
  const int t   = threadIdx.x;
  const int wv  = t >> 6;              // 8 waves
  const int q0  = ((bid & 127) << 5) + (wv << 2);   // 4 queries per wave
  const float* P = pts + (size_t)b * NPTS * 3;
  const int l   = t & 63;
  const int r   = l & 15;
  const int kg  = l >> 4;

  // ---- fill LDS with all 9216 W2 chunks (lane-linear, conflict-free) ----
#pragma unroll
  for (int i = 0; i < 18; ++i) {
    const int j = i * 512 + t;
    *(f16x8*)(sB + (size_t)j * 8) = *(const f16x8*)(W2F + (size_t)j * 8);
  }

  // ---- gathers: 4 queries, neighbor slot r each ----
  float f[4][6];
#pragma unroll
  for (int qi = 0; qi < 4; ++qi) {
    const int qq = q0 + qi;
    const int nb = idx[(((size_t)b * NPTS + qq) << 4) + r];
    const float ax = P[qq * 3 + 0], ay = P[qq * 3 + 1], az = P[qq * 3 + 2];
    f[qi][0] = P[nb * 3 + 0] - ax;
    f[qi][1] = P[nb * 3 + 1] - ay;
    f[qi][2] = P[nb * 3 + 2] - az;
    f[qi][3] = ax; f[qi][4] = ay; f[qi][5] = az;
  }

  // ---- stage layer1 -> A-fragments in registers ----
  f16x8 af[4][6];
#pragma unroll
  for (int kt = 0; kt < 6; ++kt) {
    const int h0 = kt * 32 + kg * 8;
    const f32x4 bb0 = *(const f32x4*)(b1 + h0);
    const f32x4 bb1 = *(const f32x4*)(b1 + h0 + 4);
    f32x4 w0[6], w1[6];
#pragma unroll
    for (int in = 0; in < 6; ++in) {
      w0[in] = *(const f32x4*)(W1 + in * HDIM + h0);
      w1[in] = *(const f32x4*)(W1 + in * HDIM + h0 + 4);
    }
#pragma unroll
    for (int qi = 0; qi < 4; ++qi) {
      f32x4 a0 = bb0, a1 = bb1;
#pragma unroll
      for (int in = 0; in < 6; ++in) {
        a0 += f[qi][in] * w0[in];
        a1 += f[qi][in] * w1[in];
      }
      f16x8 v;
#pragma unroll
      for (int j = 0; j < 4; ++j) {   // same swish expression (absmax-stable)
        v[j]     = (_Float16)(a0[j] * __builtin_amdgcn_rcpf(1.0f + __expf(-a0[j])));
        v[j + 4] = (_Float16)(a1[j] * __builtin_amdgcn_rcpf(1.0f + __expf(-a1[j])));
      }
      af[qi][kt] = v;
    }
  }
  __syncthreads();   // LDS fill complete (fill loads + staging overlap above)

  // ---- MFMA + maxpool over 24 channel tiles; B from LDS, software-pipelined ----
  const size_t orow = (size_t)b * NPTS + q0;
  const _Float16* bp = sB + (size_t)l * 8;   // chunk position == lane

  f16x8 bcur[6];
#pragma unroll
  for (int kt = 0; kt < 6; ++kt)
    bcur[kt] = *(const f16x8*)(bp + (size_t)kt * 512);   // ct=0

  for (int ct = 0; ct < 24; ++ct) {
    const int c = ct * 16 + r;
    // prefetch next ct's B-frags (hides LDS latency under MFMAs)
    f16x8 bnxt[6];
    const int ctn = (ct < 23) ? ct + 1 : 23;
#pragma unroll
    for (int kt = 0; kt < 6; ++kt)
      bnxt[kt] = *(const f16x8*)(bp + (size_t)(ctn * 6 + kt) * 512);

    f32x4 acc[4];
#pragma unroll
    for (int qi = 0; qi < 4; ++qi) acc[qi] = f32x4{0.f, 0.f, 0.f, 0.f};
#pragma unroll
    for (int kt = 0; kt < 6; ++kt)
#pragma unroll
      for (int qi = 0; qi < 4; ++qi)
        acc[qi] = __builtin_amdgcn_mfma_f32_16x16x32_f16(af[qi][kt], bcur[kt], acc[qi], 0, 0, 0);

    const float bb = b2[c];
    // C/D: col=lane&15 (=channel), row=(lane>>4)*4+reg (=neighbor) -> max over rows
#pragma unroll
    for (int qi = 0; qi < 4; ++qi) {
      float m = fmaxf(fmaxf(acc[qi][0], acc[qi][1]), fmaxf(acc[qi][2], acc[qi][3]));
      m = fmaxf(m, __shfl_xor(m, 16));
      m = fmaxf(m, __shfl_xor(m, 32));
      if (l < 16)
        out[(orow + qi) * CDIM + c] = m + bb;
    }

#pragma unroll
    for (int kt = 0; kt < 6; ++kt) bcur[kt] = bnxt[kt];
  }
}

extern "C" void kernel_launch(void* const* d_in, const int* in_sizes, int n_in,
                              void* d_out, int out_size, void* d_ws, size_t ws_size,
                              hipStream_t stream) {
  const float* point = (const float*)d_in[0];
  const float* W1    = (const float*)d_in[1];
  const float* b1    = (const float*)d_in[2];
  const float* W2    = (const float*)d_in[3];
  const float* b2    = (const float*)d_in[4];

  int*      idx_ws = (int*)d_ws;                                  // 1 MB
  _Float16* W2F    = (_Float16*)((char*)d_ws + (1 << 20));        // 144 KB

  prep_w2<<<36, 256, 0, stream>>>(W2, W2F);
  knn_kernel<<<512, 512, 0, stream>>>(point, idx_ws);
  mlp_kernel<<<512, 512, 0, stream>>>(point, idx_ws, W1, b1, W2F, b2, (float*)d_out);
}